// Round 1
// 73.586 us; speedup vs baseline: 1.0511x; 1.0511x over previous
//
#include <hip/hip_runtime.h>

#define N_BATCH 128
#define IN_F 1024
#define OUT_F 1024
#define BT 8              // batch rows per block
#define JT 32             // output cols per block
#define SEG 32            // K segments per block (32 i each)
#define RSTRIDE 36        // floats per row within a segment (32 + pad)
#define SSTRIDE 292       // floats per segment (8*36+4): bank-quad skew of 4/seg

// v2: same geometry as v1 (512 blocks, 2/CU), but latency-oriented:
//  - __launch_bounds__(256,2): guarantee 2 waves/SIMD (VGPR <= 256, no occupancy collapse)
//  - main loop software-pipelined: W prefetched 2 phases ahead, X (LDS) 1 phase ahead
//  - u-phase vectorized: float4 A + float4 LDS reads, 8 iters + shfl reduce (was 64 scalar)
//  - split staging (loads issued before LDS writes) + epilogue/codes loads hoisted to top
__global__ __launch_bounds__(256, 2) void geps_two(
    const float* __restrict__ input,    // [128,1024]
    const float* __restrict__ codes,    // [128,2,2]
    const float* __restrict__ weight,   // [1024,1024]
    const float* __restrict__ A,        // [1024,2]
    const float* __restrict__ Bm,       // [2,1024]
    const float* __restrict__ bias,     // [1024]
    const float* __restrict__ bctx,     // [2,1024]
    float* __restrict__ out)            // [128,1024]
{
    __shared__ __align__(16) float s[SEG * SSTRIDE];   // 37.4 KB, dual-use
    __shared__ float s_u[BT][2];
    __shared__ float s_v[BT][4];        // v0, v1, c00, c11

    const int t = threadIdx.x;
    const int j0 = blockIdx.x * JT;
    const int b0 = blockIdx.y * BT;

    // ---- issue all 8 stage loads first (stay in flight together) ----
    float4 stg[8];
    #pragma unroll
    for (int it = 0; it < 8; ++it) {
        const int F = t + 256 * it;          // float4 index, 0..2047
        const int r = F >> 8;                // row 0..7
        const int i4 = F & 255;              // float4-within-row
        stg[it] = ((const float4*)input)[(size_t)(b0 + r) * (IN_F / 4) + i4];
    }

    // ---- hoist epilogue + codes loads: cold misses overlap staging ----
    const int jcol = j0 + (t & 31);
    const float bm0 = Bm[jcol];
    const float bm1 = Bm[OUT_F + jcol];
    const float bj  = bias[jcol];
    const float bq0 = bctx[jcol];
    const float bq1 = bctx[OUT_F + jcol];

    float c00 = 0.f, c01 = 0.f, c10 = 0.f, c11 = 0.f;
    if (t < BT) {
        const int b = b0 + t;
        c00 = codes[b * 4 + 0]; c01 = codes[b * 4 + 1];
        c10 = codes[b * 4 + 2]; c11 = codes[b * 4 + 3];
    }

    // ---- write staged rows into swizzled LDS ----
    #pragma unroll
    for (int it = 0; it < 8; ++it) {
        const int F = t + 256 * it;
        const int r = F >> 8;
        const int i4 = F & 255;
        const int ks = i4 >> 3, g = i4 & 7;
        *(float4*)&s[ks * SSTRIDE + r * RSTRIDE + 4 * g] = stg[it];
    }
    __syncthreads();

    // ---- u[row][r] = dot(in_row, A[:,r]) : 8 rows x 32 lanes, float4 ----
    {
        const int row = t >> 5, l = t & 31;
        float u0 = 0.f, u1 = 0.f;
        #pragma unroll
        for (int ii = 0; ii < 8; ++ii) {
            const int i4 = l + 32 * ii;           // float4-within-row, 0..255
            const int ks = i4 >> 3, g = i4 & 7;
            const float4 x  = *(const float4*)&s[ks * SSTRIDE + row * RSTRIDE + 4 * g];
            const float4 A0 = ((const float4*)A)[2 * i4];      // A[4*i4+0..1][0..1]
            const float4 A1 = ((const float4*)A)[2 * i4 + 1];  // A[4*i4+2..3][0..1]
            u0 = fmaf(x.x, A0.x, u0); u1 = fmaf(x.x, A0.y, u1);
            u0 = fmaf(x.y, A0.z, u0); u1 = fmaf(x.y, A0.w, u1);
            u0 = fmaf(x.z, A1.x, u0); u1 = fmaf(x.z, A1.y, u1);
            u0 = fmaf(x.w, A1.z, u0); u1 = fmaf(x.w, A1.w, u1);
        }
        #pragma unroll
        for (int off = 16; off > 0; off >>= 1) {
            u0 += __shfl_down(u0, off, 32);
            u1 += __shfl_down(u1, off, 32);
        }
        if (l == 0) { s_u[row][0] = u0; s_u[row][1] = u1; }
    }
    __syncthreads();

    if (t < BT) {
        const float u0 = s_u[t][0], u1 = s_u[t][1];
        s_v[t][0] = fmaf(u0, c00, u1 * c10);   // v[b,0]
        s_v[t][1] = fmaf(u0, c01, u1 * c11);   // v[b,1]
        s_v[t][2] = c00;
        s_v[t][3] = c11;
    }
    // no sync needed: s_v consumed only after the next two barriers

    // ---- main loop: software-pipelined (W depth-2, X depth-1) ----
    const int jg = t & 7, ks = t >> 3;
    const int col4 = (j0 >> 2) + jg;
    const float4* Wc = (const float4*)weight + col4;
    const float* segbase = &s[ks * SSTRIDE];

    float4 acc[BT];
    #pragma unroll
    for (int r = 0; r < BT; ++r) acc[r] = make_float4(0.f, 0.f, 0.f, 0.f);

    float4 w0[4], w1[4], aC[BT];
    #pragma unroll
    for (int q = 0; q < 4; ++q) w0[q] = Wc[(size_t)(ks * 32 + q) * (OUT_F / 4)];
    #pragma unroll
    for (int q = 0; q < 4; ++q) w1[q] = Wc[(size_t)(ks * 32 + 4 + q) * (OUT_F / 4)];
    #pragma unroll
    for (int r = 0; r < BT; ++r) aC[r] = *(const float4*)&segbase[r * RSTRIDE];

    #pragma unroll
    for (int g = 0; g < 8; ++g) {
        float4 wn[4];
        if (g < 6) {                          // prefetch W for phase g+2
            #pragma unroll
            for (int q = 0; q < 4; ++q)
                wn[q] = Wc[(size_t)(ks * 32 + 4 * (g + 2) + q) * (OUT_F / 4)];
        }
        float4 aN[BT];
        if (g < 7) {                          // prefetch X for phase g+1
            #pragma unroll
            for (int r = 0; r < BT; ++r)
                aN[r] = *(const float4*)&segbase[r * RSTRIDE + 4 * (g + 1)];
        }
        #pragma unroll
        for (int q = 0; q < 4; ++q) {
            #pragma unroll
            for (int r = 0; r < BT; ++r) {
                const float av = (q == 0) ? aC[r].x : (q == 1) ? aC[r].y
                               : (q == 2) ? aC[r].z : aC[r].w;
                acc[r].x = fmaf(av, w0[q].x, acc[r].x);
                acc[r].y = fmaf(av, w0[q].y, acc[r].y);
                acc[r].z = fmaf(av, w0[q].z, acc[r].z);
                acc[r].w = fmaf(av, w0[q].w, acc[r].w);
            }
        }
        if (g < 7) {
            #pragma unroll
            for (int q = 0; q < 4; ++q) { w0[q] = w1[q]; w1[q] = wn[q]; }
            #pragma unroll
            for (int r = 0; r < BT; ++r) aC[r] = aN[r];
        }
    }
    __syncthreads();                         // all s reads done; s_v visible

    // ---- write partials into reused LDS buffer ----
    #pragma unroll
    for (int r = 0; r < BT; ++r)
        *(float4*)&s[ks * SSTRIDE + r * RSTRIDE + 4 * jg] = acc[r];
    __syncthreads();

    // ---- reduce across 32 segments + epilogue ----
    {
        const int row = t >> 5, col = t & 31;
        float sum = 0.f;
        #pragma unroll
        for (int k = 0; k < SEG; ++k)
            sum += s[k * SSTRIDE + row * RSTRIDE + col];

        const float v0 = s_v[row][0], v1 = s_v[row][1];
        const float k00 = s_v[row][2], k11 = s_v[row][3];
        out[(size_t)(b0 + row) * OUT_F + jcol] = sum
            + v0 * bm0 + v1 * bm1
            + bj
            + k00 * bq0 + k11 * bq1;
    }
}

extern "C" void kernel_launch(void* const* d_in, const int* in_sizes, int n_in,
                              void* d_out, int out_size, void* d_ws, size_t ws_size,
                              hipStream_t stream) {
    const float* input = (const float*)d_in[0];
    const float* codes = (const float*)d_in[1];
    const float* weight = (const float*)d_in[2];
    const float* A = (const float*)d_in[3];
    const float* Bm = (const float*)d_in[4];
    const float* bias = (const float*)d_in[5];
    const float* bctx = (const float*)d_in[6];
    float* out = (float*)d_out;

    dim3 grid(OUT_F / JT, N_BATCH / BT);   // (32, 16) = 512 blocks, 2/CU
    dim3 block(256);
    geps_two<<<grid, block, 0, stream>>>(input, codes, weight, A, Bm, bias, bctx, out);
}